// Round 10
// baseline (1710.645 us; speedup 1.0000x reference)
//
#include <hip/hip_runtime.h>

// GRU scan: T=1024, B=256, D=256.
// v10 = exact v7 (best: 1224us) + micro-cuts:
//  - kk=0 peeled with zacc C-operand -> no per-step accvgpr_write zero-init
//  - y stored as float2 from even-pair lanes (dpp_swap2 reused for h mask)
//  - HP=576 pitch (read+write verified conflict-free), pointer-increment rst
// Producer/consumer fusion, WAIT_ROUNDS, 6-acc interleave all unchanged from v7.

typedef __attribute__((ext_vector_type(8))) short short8;
typedef __attribute__((ext_vector_type(4))) float f32x4;

#define T_DIM 1024
#define B_DIM 256
#define D_DIM 256
#define SCL_RZ (-1.44269504f)   // -log2(e): sigm(x) = 1/(1+exp2(x*SCL_RZ))
#define SCL_N  (2.88539008f)    // 2*log2(e): tanh(v) = 1-2/(1+exp2(v*SCL_N))
#define HP 576                  // hb16 row pitch (bytes): +64B bank skew
#define HBUF 1152               // one h double-buffer half (2 rows x 576)

__device__ __forceinline__ unsigned short f2bf(float f) {
  union { float f; unsigned u; } c; c.f = f;
  unsigned r = c.u + 0x7FFFu + ((c.u >> 16) & 1u);  // RNE
  return (unsigned short)(r >> 16);
}
__device__ __forceinline__ float u2f(unsigned u) {
  union { unsigned u; float f; } c; c.u = u;
  return c.f;
}
__device__ __forceinline__ float dpp_shr4(float own, float src) {
  union { float f; int i; } o, s, r;
  o.f = own; s.f = src;
  r.i = __builtin_amdgcn_update_dpp(o.i, s.i, 0x114, 0xF, 0xA, false);
  return r.f;
}
__device__ __forceinline__ float dpp_shr8(float own, float src) {
  union { float f; int i; } o, s, r;
  o.f = own; s.f = src;
  r.i = __builtin_amdgcn_update_dpp(o.i, s.i, 0x118, 0xF, 0xC, false);
  return r.f;
}
__device__ __forceinline__ float dpp_shr2(float x) {
  union { float f; int i; } s, r;
  s.f = x;
  r.i = __builtin_amdgcn_update_dpp(s.i, s.i, 0x112, 0xF, 0xF, false);
  return r.f;
}
// quad_perm [2,3,0,1]: lane q gets value from lane q^2 (pair partner)
__device__ __forceinline__ float dpp_swap2(float x) {
  union { float f; int i; } s, r;
  s.f = x;
  r.i = __builtin_amdgcn_update_dpp(s.i, s.i, 0x4E, 0xF, 0xF, false);
  return r.f;
}

// resets dtype ambiguous (reference dtype bool). flags[0]=float32, flags[1]=bytes.
__global__ void detect_resets(const int* __restrict__ r, int n, int* __restrict__ flags) {
  int isf = 0, oth = 0;
  for (int i = blockIdx.x * blockDim.x + threadIdx.x; i < n; i += gridDim.x * blockDim.x) {
    int v = r[i];
    if (v == 0x3F800000) isf = 1;
    else if (v != 0 && v != 1) oth = 1;
  }
  if (isf) atomicOr(&flags[0], 1);
  if (oth) atomicOr(&flags[1], 1);
}

__device__ __forceinline__ int read_reset(const void* r, int f0, int f1, int idx) {
  if (f0) return ((const float*)r)[idx] != 0.0f;
  if (f1) return ((const unsigned char*)r)[idx] != 0;
  return ((const int*)r)[idx] != 0;
}

__global__ void convert_resets(const void* __restrict__ rst, const int* __restrict__ flags,
                               unsigned char* __restrict__ rst8) {
  int f0 = flags[0], f1 = flags[1];
  for (int i = blockIdx.x * blockDim.x + threadIdx.x; i < T_DIM * B_DIM;
       i += gridDim.x * blockDim.x)
    rst8[i] = (unsigned char)read_reset(rst, f0, f1, i);
}

// Pack WiT (768x256 bf16, transposed Wi, PRE-SCALED per output col) and Wpk A-frags
// (PRE-SCALED): frag(dt,ks) elem (l,j) = scl(dt)*W[ks*32+(l>>4)*8+j][dt*16+(l&15)].
__global__ void pack_weights(const float* __restrict__ Wi,
                             const float* __restrict__ Whr,
                             const float* __restrict__ Whz,
                             const float* __restrict__ Whn,
                             unsigned short* __restrict__ WiT,
                             unsigned short* __restrict__ Wpk) {
  int gid = blockIdx.x * 256 + threadIdx.x;
  const int NE = 768 * 256;
  if (gid < NE) {
    int n = gid >> 8, k = gid & 255;
    float scl = (n < 512) ? SCL_RZ : SCL_N;
    WiT[gid] = f2bf(Wi[k * 768 + n] * scl);
  } else if (gid < 2 * NE) {
    int g = gid - NE;
    int j = g & 7, l = (g >> 3) & 63, ks = (g >> 9) & 7, nt = g >> 12;
    int k = ks * 32 + (l >> 4) * 8 + j;
    int col = nt * 16 + (l & 15);
    float w;
    if (col < 256)      w = Whr[k * 256 + col] * SCL_RZ;
    else if (col < 512) w = Whz[k * 256 + col - 256] * SCL_RZ;
    else                w = Whn[k * 256 + col - 512] * SCL_N;
    Wpk[g] = f2bf(w);
  }
}

// Fused kernel. even blockIdx -> scan WG (2 batch rows); odd -> producer WG.
// Producers compute xp in rounds of 128 m-blocks (64 t-steps), publish rc[r].
__global__ __launch_bounds__(512, 2) void fused(
    const float* __restrict__ x, const unsigned short* __restrict__ WiT,
    const float* __restrict__ bi, unsigned short* __restrict__ xp,
    const unsigned char* __restrict__ rst8, const float* __restrict__ bhn,
    const unsigned short* __restrict__ Wpk, float* __restrict__ y,
    float* __restrict__ hws, int* __restrict__ rc, int t0, int Tc) {
  __shared__ __align__(16) char smem[32768];
  const int tid = threadIdx.x;

  if (blockIdx.x & 1) {
    // ================= producer: xp = x@Wi_scaled + bi_scaled =================
    unsigned short* Al = (unsigned short*)smem;            // 128x64 bf16, swizzled
    unsigned short* Bl = (unsigned short*)(smem + 16384);  // 128x64 bf16, swizzled
    const int pw = blockIdx.x >> 1;
    const int l = tid & 63, wid = tid >> 6;
    const int wm = wid >> 2, wn = wid & 3;   // 2x4 wave grid over 128x128 tile
    const int Mc = Tc * 2;
    const int rounds = (Mc + 127) >> 7;
    for (int r = 0; r < rounds; ++r) {
      const int mb = r * 128 + pw;
      if (mb < Mc) {
        const long m0 = (long)mb * 128;
        for (int nb = 0; nb < 6; ++nb) {
          const int n0 = nb * 128;
          f32x4 acc[4][2] = {};
          for (int kb = 0; kb < 4; ++kb) {
            const int k0 = kb * 64;
            __syncthreads();
#pragma unroll
            for (int i = 0; i < 4; ++i) {  // stage A (x fp32 -> bf16)
              int fidx = i * 512 + tid;
              int row = fidx >> 4, kf = fidx & 15;
              float4 v = *(const float4*)&x[(m0 + row) * 256 + k0 + kf * 4];
              uint2 pk;
              pk.x = f2bf(v.x) | ((unsigned)f2bf(v.y) << 16);
              pk.y = f2bf(v.z) | ((unsigned)f2bf(v.w) << 16);
              int byte = (row * 128 + kf * 8) ^ ((row & 7) << 4);
              *(uint2*)((char*)Al + byte) = pk;
            }
#pragma unroll
            for (int i = 0; i < 2; ++i) {  // stage B (WiT bf16)
              int cidx = i * 512 + tid;
              int row = cidx >> 3, kc = cidx & 7;
              short8 v = *(const short8*)&WiT[(n0 + row) * 256 + k0 + kc * 8];
              int byte = (row * 128 + kc * 16) ^ ((row & 7) << 4);
              *(short8*)((char*)Bl + byte) = v;
            }
            __syncthreads();
#pragma unroll
            for (int kk = 0; kk < 2; ++kk) {
              short8 af[4], bfv[2];
#pragma unroll
              for (int t = 0; t < 4; ++t) {
                int m = wm * 64 + t * 16 + (l & 15);
                af[t] = *(const short8*)((char*)Al + ((m * 128 + kk * 64 + (l >> 4) * 16) ^ ((m & 7) << 4)));
              }
#pragma unroll
              for (int u = 0; u < 2; ++u) {
                int n = wn * 32 + u * 16 + (l & 15);
                bfv[u] = *(const short8*)((char*)Bl + ((n * 128 + kk * 64 + (l >> 4) * 16) ^ ((n & 7) << 4)));
              }
#pragma unroll
              for (int tm = 0; tm < 4; ++tm)
#pragma unroll
                for (int tn = 0; tn < 2; ++tn)
                  acc[tm][tn] = __builtin_amdgcn_mfma_f32_16x16x32_bf16(af[tm], bfv[tn], acc[tm][tn], 0, 0, 0);
            }
          }
#pragma unroll
          for (int tn = 0; tn < 2; ++tn) {
            int n = n0 + wn * 32 + tn * 16 + (l & 15);
            float bscl = bi[n] * ((n < 512) ? SCL_RZ : SCL_N);
#pragma unroll
            for (int tm = 0; tm < 4; ++tm) {
#pragma unroll
              for (int rr = 0; rr < 4; ++rr) {
                long m = m0 + wm * 64 + tm * 16 + (l >> 4) * 4 + rr;
                xp[m * 768 + n] = f2bf(acc[tm][tn][rr] + bscl);
              }
            }
          }
        }
      }
      __syncthreads();  // all waves' stores issued before the flag
      if (tid == 0)
        __hip_atomic_fetch_add(&rc[r], 1, __ATOMIC_RELEASE, __HIP_MEMORY_SCOPE_AGENT);
    }
    return;
  }

  // ================= consumer: recurrent scan (v7 schedule) =================
  char* hb16 = smem;  // [2][HBUF] bytes, pitch HP per batch row
  const int l = tid & 63, w = tid >> 6;
  const int p = l & 15, grp = l >> 4;
  const int b = p & 1;
  const int B0 = (blockIdx.x >> 1) * 2;
  const bool odd1 = (p >> 1) & 1;
  const int d0 = w * 32 + ((p >> 2) & 1) * 16 + grp * 4 + ((p >> 3) & 1) * 2 + ((p >> 1) & 1);

  // all 48 weight frags into registers/AGPRs
  short8 wreg[48];
#pragma unroll
  for (int t = 0; t < 6; ++t) {
    int dt = (t >> 1) * 16 + w * 2 + (t & 1);
#pragma unroll
    for (int kk = 0; kk < 8; ++kk)
      wreg[t * 8 + kk] = *(const short8*)&Wpk[((dt * 8 + kk) * 64 + l) * 8];
  }
  const float bh = bhn[d0] * SCL_N;
  const f32x4 zacc = {0.f, 0.f, 0.f, 0.f};  // loop-invariant MFMA C for kk=0

  // init h (1 elem) + hb16 buffer 0
  float h = 0.f;
  if (t0 > 0) {
    float hv = hws[(B0 + b) * 256 + d0];
    if (!rst8[t0 * 256 + B0 + b]) h = hv;
  }
  {
    unsigned hp;
    asm("v_cvt_pk_bf16_f32 %0, %1, %2" : "=v"(hp) : "v"(h), "v"(h));
    *(unsigned short*)(hb16 + b * HP + d0 * 2) = (unsigned short)hp;
  }
  __syncthreads();

  // wait for xp round 0, then prefetch step 0
  int done_rounds = 0;
#define WAIT_ROUNDS(rneed)                                                              \
  while (done_rounds <= (rneed)) {                                                     \
    int c_ = __hip_atomic_load(&rc[done_rounds], __ATOMIC_ACQUIRE,                     \
                               __HIP_MEMORY_SCOPE_AGENT);                              \
    if (c_ == 128) ++done_rounds;                                                      \
    else __builtin_amdgcn_s_sleep(8);                                                  \
  }
  WAIT_ROUNDS(0)

  const unsigned short* xpp = xp + ((long)(B0 + b)) * 768 + d0;
  float* yp = y + ((long)t0 * 256 + B0 + b) * 256 + d0;
  unsigned xr_ = *(const unsigned short*)(xpp);
  unsigned xz_ = *(const unsigned short*)(xpp + 256);
  unsigned xn_ = *(const unsigned short*)(xpp + 512);
  xpp += 256 * 768;
  const unsigned char* rp = rst8 + (t0 + 1) * 256 + B0 + b;
  int rstn = (t0 + 1 < T_DIM) ? (int)rp[0] : 0;
  rp += 256;
  const char* hrd = hb16 + b * HP + grp * 16;   // frag read base
  char* hwr = hb16 + b * HP + d0 * 2;           // merged write base (even-d0 lanes)

  for (int ts = 0; ts < Tc; ++ts) {
    const int cur = ts & 1, nxt = cur ^ 1;
    const char* hb = hrd + cur * HBUF;
#define LDH(k) (*(const short8*)(hb + (k) * 64))
    // ---- 48 MFMA, 6-acc interleave (v7 schedule), kk=0 peeled with zacc C ----
    short8 hf[3];
    hf[0] = LDH(0); hf[1] = LDH(1);
    __builtin_amdgcn_s_setprio(1);
    f32x4 az0 = __builtin_amdgcn_mfma_f32_16x16x32_bf16(wreg[16], hf[0], zacc, 0, 0, 0);
    f32x4 az1 = __builtin_amdgcn_mfma_f32_16x16x32_bf16(wreg[24], hf[0], zacc, 0, 0, 0);
    f32x4 ar0 = __builtin_amdgcn_mfma_f32_16x16x32_bf16(wreg[0],  hf[0], zacc, 0, 0, 0);
    f32x4 ar1 = __builtin_amdgcn_mfma_f32_16x16x32_bf16(wreg[8],  hf[0], zacc, 0, 0, 0);
    f32x4 an0 = __builtin_amdgcn_mfma_f32_16x16x32_bf16(wreg[32], hf[0], zacc, 0, 0, 0);
    f32x4 an1 = __builtin_amdgcn_mfma_f32_16x16x32_bf16(wreg[40], hf[0], zacc, 0, 0, 0);
    hf[2] = LDH(2);
#pragma unroll
    for (int kk = 1; kk < 8; ++kk) {
      if (kk + 2 < 8) hf[(kk + 2) % 3] = LDH(kk + 2);
      const int s_ = kk % 3;
      az0 = __builtin_amdgcn_mfma_f32_16x16x32_bf16(wreg[16 + kk], hf[s_], az0, 0, 0, 0);
      az1 = __builtin_amdgcn_mfma_f32_16x16x32_bf16(wreg[24 + kk], hf[s_], az1, 0, 0, 0);
      ar0 = __builtin_amdgcn_mfma_f32_16x16x32_bf16(wreg[kk],      hf[s_], ar0, 0, 0, 0);
      ar1 = __builtin_amdgcn_mfma_f32_16x16x32_bf16(wreg[8 + kk],  hf[s_], ar1, 0, 0, 0);
      an0 = __builtin_amdgcn_mfma_f32_16x16x32_bf16(wreg[32 + kk], hf[s_], an0, 0, 0, 0);
      an1 = __builtin_amdgcn_mfma_f32_16x16x32_bf16(wreg[40 + kk], hf[s_], an1, 0, 0, 0);
    }
    __builtin_amdgcn_s_setprio(0);
#undef LDH
    // ---- 3-stage fold: 6 accs -> 1 elem/lane per gate ----
    float aR, aZ, aN;
    {
      float f0, f1, f2, f3, g0, g1;
      f0 = dpp_shr4(az0[0], az1[0]); f1 = dpp_shr4(az0[1], az1[1]);
      f2 = dpp_shr4(az0[2], az1[2]); f3 = dpp_shr4(az0[3], az1[3]);
      g0 = dpp_shr8(f0, f2); g1 = dpp_shr8(f1, f3);
      aZ = odd1 ? dpp_shr2(g1) : g0;
      f0 = dpp_shr4(ar0[0], ar1[0]); f1 = dpp_shr4(ar0[1], ar1[1]);
      f2 = dpp_shr4(ar0[2], ar1[2]); f3 = dpp_shr4(ar0[3], ar1[3]);
      g0 = dpp_shr8(f0, f2); g1 = dpp_shr8(f1, f3);
      aR = odd1 ? dpp_shr2(g1) : g0;
      f0 = dpp_shr4(an0[0], an1[0]); f1 = dpp_shr4(an0[1], an1[1]);
      f2 = dpp_shr4(an0[2], an1[2]); f3 = dpp_shr4(an0[3], an1[3]);
      g0 = dpp_shr8(f0, f2); g1 = dpp_shr8(f1, f3);
      aN = odd1 ? dpp_shr2(g1) : g0;
    }
    // ---- gates: 1 elem, exp2-direct (3 exp2 + 2 rcp) ----
    float den_r = 1.0f + exp2f(fminf(u2f(xr_ << 16) + aR, 14.f));
    float den_z = 1.0f + exp2f(fminf(u2f(xz_ << 16) + aZ, 14.f));
    float s = __builtin_amdgcn_rcpf(den_r * den_z);
    float rg = den_z * s;   // 1/den_r
    float zg = den_r * s;   // 1/den_z
    float cden = 1.0f + exp2f(fminf(fmaf(rg, aN + bh, u2f(xn_ << 16)), 14.f));
    float ic = __builtin_amdgcn_rcpf(cden);
    float ng = fmaf(-2.0f, ic, 1.0f);            // tanh
    float o = fmaf(zg, h - ng, ng);              // o = n + z*(h-n)
    // partner value once: feeds BOTH the paired y-store and the h pack
    float oq = dpp_swap2(o);
    if ((p & 2) == 0) {     // even-d0 lanes store (y[d0], y[d0+1]) as float2
      float2 o2 = {o, oq};
      *(float2*)yp = o2;
    }
    yp += 256 * 256;
    // carry (mask with next step's reset); pair-merged dword write to hb16[nxt]
    h = rstn ? 0.f : o;
    {
      float hq = rstn ? 0.f : oq;
      if ((p & 2) == 0) {
        unsigned hp;
        asm("v_cvt_pk_bf16_f32 %0, %1, %2" : "=v"(hp) : "v"(h), "v"(hq));
        *(unsigned*)(hwr + nxt * HBUF) = hp;
      }
    }
    // prefetch next step (vmcnt NOT drained at barrier)
    if (ts + 1 < Tc) {
      WAIT_ROUNDS((2 * ts + 3) >> 7)
      xr_ = *(const unsigned short*)(xpp);
      xz_ = *(const unsigned short*)(xpp + 256);
      xn_ = *(const unsigned short*)(xpp + 512);
      xpp += 256 * 768;
      int tg = t0 + ts;
      rstn = (tg + 2 < T_DIM) ? (int)rp[0] : 0;
      rp += 256;
    }
    asm volatile("s_waitcnt lgkmcnt(0)" ::: "memory");
    __builtin_amdgcn_s_barrier();
  }
#undef WAIT_ROUNDS
  hws[(B0 + b) * 256 + d0] = h;
}

extern "C" void kernel_launch(void* const* d_in, const int* in_sizes, int n_in,
                              void* d_out, int out_size, void* d_ws, size_t ws_size,
                              hipStream_t stream) {
  const float* x    = (const float*)d_in[0];
  const void*  rst  = d_in[1];
  const float* Wi   = (const float*)d_in[2];
  const float* bi   = (const float*)d_in[3];
  const float* Whr  = (const float*)d_in[4];
  const float* Whz  = (const float*)d_in[5];
  const float* Whn  = (const float*)d_in[6];
  const float* bhn  = (const float*)d_in[7];
  float* y = (float*)d_out;

  char* ws = (char*)d_ws;
  unsigned short* Wpk = (unsigned short*)(ws);              // 393216 B
  unsigned short* WiT = (unsigned short*)(ws + 393216);     // 393216 B
  float* hws          = (float*)(ws + 786432);              // 262144 B
  int* flags          = (int*)(ws + 1048576);               // 64 B
  int* rc             = (int*)(ws + 1048640);               // 64 B (16 rounds)
  unsigned char* rst8 = (unsigned char*)(ws + 1048832);     // 262144 B
  unsigned short* xpb = (unsigned short*)(ws + 1310976);

  const size_t fixed = 1310976;
  int Tc = T_DIM;
  while (Tc > 1 && fixed + (size_t)Tc * B_DIM * 768 * 2 > ws_size) Tc >>= 1;

  hipMemsetAsync(flags, 0, 8, stream);
  detect_resets<<<64, 256, 0, stream>>>((const int*)rst, T_DIM * B_DIM / 4, flags);
  convert_resets<<<256, 256, 0, stream>>>(rst, flags, rst8);
  pack_weights<<<1536, 256, 0, stream>>>(Wi, Whr, Whz, Whn, WiT, Wpk);
  for (int t0 = 0; t0 < T_DIM; t0 += Tc) {
    hipMemsetAsync(rc, 0, 64, stream);
    fused<<<256, 512, 0, stream>>>(x + (long)t0 * B_DIM * D_DIM, WiT, bi, xpb,
                                   rst8, bhn, Wpk, y, hws, rc, t0, Tc);
  }
}

// Round 11
// 1710.428 us; speedup vs baseline: 1.0001x; 1.0001x over previous
//
#include <hip/hip_runtime.h>

// GRU scan: T=1024, B=256, D=256.
// v10 = exact v7 (best: 1224us) + micro-cuts:
//  - kk=0 peeled with zacc C-operand -> no per-step accvgpr_write zero-init
//  - y stored as float2 from even-pair lanes (dpp_swap2 reused for h mask)
//  - HP=576 pitch (read+write verified conflict-free), pointer-increment rst
// Producer/consumer fusion, WAIT_ROUNDS, 6-acc interleave all unchanged from v7.

typedef __attribute__((ext_vector_type(8))) short short8;
typedef __attribute__((ext_vector_type(4))) float f32x4;

#define T_DIM 1024
#define B_DIM 256
#define D_DIM 256
#define SCL_RZ (-1.44269504f)   // -log2(e): sigm(x) = 1/(1+exp2(x*SCL_RZ))
#define SCL_N  (2.88539008f)    // 2*log2(e): tanh(v) = 1-2/(1+exp2(v*SCL_N))
#define HP 576                  // hb16 row pitch (bytes): +64B bank skew
#define HBUF 1152               // one h double-buffer half (2 rows x 576)

__device__ __forceinline__ unsigned short f2bf(float f) {
  union { float f; unsigned u; } c; c.f = f;
  unsigned r = c.u + 0x7FFFu + ((c.u >> 16) & 1u);  // RNE
  return (unsigned short)(r >> 16);
}
__device__ __forceinline__ float u2f(unsigned u) {
  union { unsigned u; float f; } c; c.u = u;
  return c.f;
}
__device__ __forceinline__ float dpp_shr4(float own, float src) {
  union { float f; int i; } o, s, r;
  o.f = own; s.f = src;
  r.i = __builtin_amdgcn_update_dpp(o.i, s.i, 0x114, 0xF, 0xA, false);
  return r.f;
}
__device__ __forceinline__ float dpp_shr8(float own, float src) {
  union { float f; int i; } o, s, r;
  o.f = own; s.f = src;
  r.i = __builtin_amdgcn_update_dpp(o.i, s.i, 0x118, 0xF, 0xC, false);
  return r.f;
}
__device__ __forceinline__ float dpp_shr2(float x) {
  union { float f; int i; } s, r;
  s.f = x;
  r.i = __builtin_amdgcn_update_dpp(s.i, s.i, 0x112, 0xF, 0xF, false);
  return r.f;
}
// quad_perm [2,3,0,1]: lane q gets value from lane q^2 (pair partner)
__device__ __forceinline__ float dpp_swap2(float x) {
  union { float f; int i; } s, r;
  s.f = x;
  r.i = __builtin_amdgcn_update_dpp(s.i, s.i, 0x4E, 0xF, 0xF, false);
  return r.f;
}

// resets dtype ambiguous (reference dtype bool). flags[0]=float32, flags[1]=bytes.
__global__ void detect_resets(const int* __restrict__ r, int n, int* __restrict__ flags) {
  int isf = 0, oth = 0;
  for (int i = blockIdx.x * blockDim.x + threadIdx.x; i < n; i += gridDim.x * blockDim.x) {
    int v = r[i];
    if (v == 0x3F800000) isf = 1;
    else if (v != 0 && v != 1) oth = 1;
  }
  if (isf) atomicOr(&flags[0], 1);
  if (oth) atomicOr(&flags[1], 1);
}

__device__ __forceinline__ int read_reset(const void* r, int f0, int f1, int idx) {
  if (f0) return ((const float*)r)[idx] != 0.0f;
  if (f1) return ((const unsigned char*)r)[idx] != 0;
  return ((const int*)r)[idx] != 0;
}

__global__ void convert_resets(const void* __restrict__ rst, const int* __restrict__ flags,
                               unsigned char* __restrict__ rst8) {
  int f0 = flags[0], f1 = flags[1];
  for (int i = blockIdx.x * blockDim.x + threadIdx.x; i < T_DIM * B_DIM;
       i += gridDim.x * blockDim.x)
    rst8[i] = (unsigned char)read_reset(rst, f0, f1, i);
}

// Pack WiT (768x256 bf16, transposed Wi, PRE-SCALED per output col) and Wpk A-frags
// (PRE-SCALED): frag(dt,ks) elem (l,j) = scl(dt)*W[ks*32+(l>>4)*8+j][dt*16+(l&15)].
__global__ void pack_weights(const float* __restrict__ Wi,
                             const float* __restrict__ Whr,
                             const float* __restrict__ Whz,
                             const float* __restrict__ Whn,
                             unsigned short* __restrict__ WiT,
                             unsigned short* __restrict__ Wpk) {
  int gid = blockIdx.x * 256 + threadIdx.x;
  const int NE = 768 * 256;
  if (gid < NE) {
    int n = gid >> 8, k = gid & 255;
    float scl = (n < 512) ? SCL_RZ : SCL_N;
    WiT[gid] = f2bf(Wi[k * 768 + n] * scl);
  } else if (gid < 2 * NE) {
    int g = gid - NE;
    int j = g & 7, l = (g >> 3) & 63, ks = (g >> 9) & 7, nt = g >> 12;
    int k = ks * 32 + (l >> 4) * 8 + j;
    int col = nt * 16 + (l & 15);
    float w;
    if (col < 256)      w = Whr[k * 256 + col] * SCL_RZ;
    else if (col < 512) w = Whz[k * 256 + col - 256] * SCL_RZ;
    else                w = Whn[k * 256 + col - 512] * SCL_N;
    Wpk[g] = f2bf(w);
  }
}

// Fused kernel. even blockIdx -> scan WG (2 batch rows); odd -> producer WG.
// Producers compute xp in rounds of 128 m-blocks (64 t-steps), publish rc[r].
__global__ __launch_bounds__(512, 2) void fused(
    const float* __restrict__ x, const unsigned short* __restrict__ WiT,
    const float* __restrict__ bi, unsigned short* __restrict__ xp,
    const unsigned char* __restrict__ rst8, const float* __restrict__ bhn,
    const unsigned short* __restrict__ Wpk, float* __restrict__ y,
    float* __restrict__ hws, int* __restrict__ rc, int t0, int Tc) {
  __shared__ __align__(16) char smem[32768];
  const int tid = threadIdx.x;

  if (blockIdx.x & 1) {
    // ================= producer: xp = x@Wi_scaled + bi_scaled =================
    unsigned short* Al = (unsigned short*)smem;            // 128x64 bf16, swizzled
    unsigned short* Bl = (unsigned short*)(smem + 16384);  // 128x64 bf16, swizzled
    const int pw = blockIdx.x >> 1;
    const int l = tid & 63, wid = tid >> 6;
    const int wm = wid >> 2, wn = wid & 3;   // 2x4 wave grid over 128x128 tile
    const int Mc = Tc * 2;
    const int rounds = (Mc + 127) >> 7;
    for (int r = 0; r < rounds; ++r) {
      const int mb = r * 128 + pw;
      if (mb < Mc) {
        const long m0 = (long)mb * 128;
        for (int nb = 0; nb < 6; ++nb) {
          const int n0 = nb * 128;
          f32x4 acc[4][2] = {};
          for (int kb = 0; kb < 4; ++kb) {
            const int k0 = kb * 64;
            __syncthreads();
#pragma unroll
            for (int i = 0; i < 4; ++i) {  // stage A (x fp32 -> bf16)
              int fidx = i * 512 + tid;
              int row = fidx >> 4, kf = fidx & 15;
              float4 v = *(const float4*)&x[(m0 + row) * 256 + k0 + kf * 4];
              uint2 pk;
              pk.x = f2bf(v.x) | ((unsigned)f2bf(v.y) << 16);
              pk.y = f2bf(v.z) | ((unsigned)f2bf(v.w) << 16);
              int byte = (row * 128 + kf * 8) ^ ((row & 7) << 4);
              *(uint2*)((char*)Al + byte) = pk;
            }
#pragma unroll
            for (int i = 0; i < 2; ++i) {  // stage B (WiT bf16)
              int cidx = i * 512 + tid;
              int row = cidx >> 3, kc = cidx & 7;
              short8 v = *(const short8*)&WiT[(n0 + row) * 256 + k0 + kc * 8];
              int byte = (row * 128 + kc * 16) ^ ((row & 7) << 4);
              *(short8*)((char*)Bl + byte) = v;
            }
            __syncthreads();
#pragma unroll
            for (int kk = 0; kk < 2; ++kk) {
              short8 af[4], bfv[2];
#pragma unroll
              for (int t = 0; t < 4; ++t) {
                int m = wm * 64 + t * 16 + (l & 15);
                af[t] = *(const short8*)((char*)Al + ((m * 128 + kk * 64 + (l >> 4) * 16) ^ ((m & 7) << 4)));
              }
#pragma unroll
              for (int u = 0; u < 2; ++u) {
                int n = wn * 32 + u * 16 + (l & 15);
                bfv[u] = *(const short8*)((char*)Bl + ((n * 128 + kk * 64 + (l >> 4) * 16) ^ ((n & 7) << 4)));
              }
#pragma unroll
              for (int tm = 0; tm < 4; ++tm)
#pragma unroll
                for (int tn = 0; tn < 2; ++tn)
                  acc[tm][tn] = __builtin_amdgcn_mfma_f32_16x16x32_bf16(af[tm], bfv[tn], acc[tm][tn], 0, 0, 0);
            }
          }
#pragma unroll
          for (int tn = 0; tn < 2; ++tn) {
            int n = n0 + wn * 32 + tn * 16 + (l & 15);
            float bscl = bi[n] * ((n < 512) ? SCL_RZ : SCL_N);
#pragma unroll
            for (int tm = 0; tm < 4; ++tm) {
#pragma unroll
              for (int rr = 0; rr < 4; ++rr) {
                long m = m0 + wm * 64 + tm * 16 + (l >> 4) * 4 + rr;
                xp[m * 768 + n] = f2bf(acc[tm][tn][rr] + bscl);
              }
            }
          }
        }
      }
      __syncthreads();  // all waves' stores issued before the flag
      if (tid == 0)
        __hip_atomic_fetch_add(&rc[r], 1, __ATOMIC_RELEASE, __HIP_MEMORY_SCOPE_AGENT);
    }
    return;
  }

  // ================= consumer: recurrent scan (v7 schedule) =================
  char* hb16 = smem;  // [2][HBUF] bytes, pitch HP per batch row
  const int l = tid & 63, w = tid >> 6;
  const int p = l & 15, grp = l >> 4;
  const int b = p & 1;
  const int B0 = (blockIdx.x >> 1) * 2;
  const bool odd1 = (p >> 1) & 1;
  const int d0 = w * 32 + ((p >> 2) & 1) * 16 + grp * 4 + ((p >> 3) & 1) * 2 + ((p >> 1) & 1);

  // all 48 weight frags into registers/AGPRs
  short8 wreg[48];
#pragma unroll
  for (int t = 0; t < 6; ++t) {
    int dt = (t >> 1) * 16 + w * 2 + (t & 1);
#pragma unroll
    for (int kk = 0; kk < 8; ++kk)
      wreg[t * 8 + kk] = *(const short8*)&Wpk[((dt * 8 + kk) * 64 + l) * 8];
  }
  const float bh = bhn[d0] * SCL_N;
  const f32x4 zacc = {0.f, 0.f, 0.f, 0.f};  // loop-invariant MFMA C for kk=0

  // init h (1 elem) + hb16 buffer 0
  float h = 0.f;
  if (t0 > 0) {
    float hv = hws[(B0 + b) * 256 + d0];
    if (!rst8[t0 * 256 + B0 + b]) h = hv;
  }
  {
    unsigned hp;
    asm("v_cvt_pk_bf16_f32 %0, %1, %2" : "=v"(hp) : "v"(h), "v"(h));
    *(unsigned short*)(hb16 + b * HP + d0 * 2) = (unsigned short)hp;
  }
  __syncthreads();

  // wait for xp round 0, then prefetch step 0
  int done_rounds = 0;
#define WAIT_ROUNDS(rneed)                                                              \
  while (done_rounds <= (rneed)) {                                                     \
    int c_ = __hip_atomic_load(&rc[done_rounds], __ATOMIC_ACQUIRE,                     \
                               __HIP_MEMORY_SCOPE_AGENT);                              \
    if (c_ == 128) ++done_rounds;                                                      \
    else __builtin_amdgcn_s_sleep(8);                                                  \
  }
  WAIT_ROUNDS(0)

  const unsigned short* xpp = xp + ((long)(B0 + b)) * 768 + d0;
  float* yp = y + ((long)t0 * 256 + B0 + b) * 256 + d0;
  unsigned xr_ = *(const unsigned short*)(xpp);
  unsigned xz_ = *(const unsigned short*)(xpp + 256);
  unsigned xn_ = *(const unsigned short*)(xpp + 512);
  xpp += 256 * 768;
  const unsigned char* rp = rst8 + (t0 + 1) * 256 + B0 + b;
  int rstn = (t0 + 1 < T_DIM) ? (int)rp[0] : 0;
  rp += 256;
  const char* hrd = hb16 + b * HP + grp * 16;   // frag read base
  char* hwr = hb16 + b * HP + d0 * 2;           // merged write base (even-d0 lanes)

  for (int ts = 0; ts < Tc; ++ts) {
    const int cur = ts & 1, nxt = cur ^ 1;
    const char* hb = hrd + cur * HBUF;
#define LDH(k) (*(const short8*)(hb + (k) * 64))
    // ---- 48 MFMA, 6-acc interleave (v7 schedule), kk=0 peeled with zacc C ----
    short8 hf[3];
    hf[0] = LDH(0); hf[1] = LDH(1);
    __builtin_amdgcn_s_setprio(1);
    f32x4 az0 = __builtin_amdgcn_mfma_f32_16x16x32_bf16(wreg[16], hf[0], zacc, 0, 0, 0);
    f32x4 az1 = __builtin_amdgcn_mfma_f32_16x16x32_bf16(wreg[24], hf[0], zacc, 0, 0, 0);
    f32x4 ar0 = __builtin_amdgcn_mfma_f32_16x16x32_bf16(wreg[0],  hf[0], zacc, 0, 0, 0);
    f32x4 ar1 = __builtin_amdgcn_mfma_f32_16x16x32_bf16(wreg[8],  hf[0], zacc, 0, 0, 0);
    f32x4 an0 = __builtin_amdgcn_mfma_f32_16x16x32_bf16(wreg[32], hf[0], zacc, 0, 0, 0);
    f32x4 an1 = __builtin_amdgcn_mfma_f32_16x16x32_bf16(wreg[40], hf[0], zacc, 0, 0, 0);
    hf[2] = LDH(2);
#pragma unroll
    for (int kk = 1; kk < 8; ++kk) {
      if (kk + 2 < 8) hf[(kk + 2) % 3] = LDH(kk + 2);
      const int s_ = kk % 3;
      az0 = __builtin_amdgcn_mfma_f32_16x16x32_bf16(wreg[16 + kk], hf[s_], az0, 0, 0, 0);
      az1 = __builtin_amdgcn_mfma_f32_16x16x32_bf16(wreg[24 + kk], hf[s_], az1, 0, 0, 0);
      ar0 = __builtin_amdgcn_mfma_f32_16x16x32_bf16(wreg[kk],      hf[s_], ar0, 0, 0, 0);
      ar1 = __builtin_amdgcn_mfma_f32_16x16x32_bf16(wreg[8 + kk],  hf[s_], ar1, 0, 0, 0);
      an0 = __builtin_amdgcn_mfma_f32_16x16x32_bf16(wreg[32 + kk], hf[s_], an0, 0, 0, 0);
      an1 = __builtin_amdgcn_mfma_f32_16x16x32_bf16(wreg[40 + kk], hf[s_], an1, 0, 0, 0);
    }
    __builtin_amdgcn_s_setprio(0);
#undef LDH
    // ---- 3-stage fold: 6 accs -> 1 elem/lane per gate ----
    float aR, aZ, aN;
    {
      float f0, f1, f2, f3, g0, g1;
      f0 = dpp_shr4(az0[0], az1[0]); f1 = dpp_shr4(az0[1], az1[1]);
      f2 = dpp_shr4(az0[2], az1[2]); f3 = dpp_shr4(az0[3], az1[3]);
      g0 = dpp_shr8(f0, f2); g1 = dpp_shr8(f1, f3);
      aZ = odd1 ? dpp_shr2(g1) : g0;
      f0 = dpp_shr4(ar0[0], ar1[0]); f1 = dpp_shr4(ar0[1], ar1[1]);
      f2 = dpp_shr4(ar0[2], ar1[2]); f3 = dpp_shr4(ar0[3], ar1[3]);
      g0 = dpp_shr8(f0, f2); g1 = dpp_shr8(f1, f3);
      aR = odd1 ? dpp_shr2(g1) : g0;
      f0 = dpp_shr4(an0[0], an1[0]); f1 = dpp_shr4(an0[1], an1[1]);
      f2 = dpp_shr4(an0[2], an1[2]); f3 = dpp_shr4(an0[3], an1[3]);
      g0 = dpp_shr8(f0, f2); g1 = dpp_shr8(f1, f3);
      aN = odd1 ? dpp_shr2(g1) : g0;
    }
    // ---- gates: 1 elem, exp2-direct (3 exp2 + 2 rcp) ----
    float den_r = 1.0f + exp2f(fminf(u2f(xr_ << 16) + aR, 14.f));
    float den_z = 1.0f + exp2f(fminf(u2f(xz_ << 16) + aZ, 14.f));
    float s = __builtin_amdgcn_rcpf(den_r * den_z);
    float rg = den_z * s;   // 1/den_r
    float zg = den_r * s;   // 1/den_z
    float cden = 1.0f + exp2f(fminf(fmaf(rg, aN + bh, u2f(xn_ << 16)), 14.f));
    float ic = __builtin_amdgcn_rcpf(cden);
    float ng = fmaf(-2.0f, ic, 1.0f);            // tanh
    float o = fmaf(zg, h - ng, ng);              // o = n + z*(h-n)
    // partner value once: feeds BOTH the paired y-store and the h pack
    float oq = dpp_swap2(o);
    if ((p & 2) == 0) {     // even-d0 lanes store (y[d0], y[d0+1]) as float2
      float2 o2 = {o, oq};
      *(float2*)yp = o2;
    }
    yp += 256 * 256;
    // carry (mask with next step's reset); pair-merged dword write to hb16[nxt]
    h = rstn ? 0.f : o;
    {
      float hq = rstn ? 0.f : oq;
      if ((p & 2) == 0) {
        unsigned hp;
        asm("v_cvt_pk_bf16_f32 %0, %1, %2" : "=v"(hp) : "v"(h), "v"(hq));
        *(unsigned*)(hwr + nxt * HBUF) = hp;
      }
    }
    // prefetch next step (vmcnt NOT drained at barrier)
    if (ts + 1 < Tc) {
      WAIT_ROUNDS((2 * ts + 3) >> 7)
      xr_ = *(const unsigned short*)(xpp);
      xz_ = *(const unsigned short*)(xpp + 256);
      xn_ = *(const unsigned short*)(xpp + 512);
      xpp += 256 * 768;
      int tg = t0 + ts;
      rstn = (tg + 2 < T_DIM) ? (int)rp[0] : 0;
      rp += 256;
    }
    asm volatile("s_waitcnt lgkmcnt(0)" ::: "memory");
    __builtin_amdgcn_s_barrier();
  }
#undef WAIT_ROUNDS
  hws[(B0 + b) * 256 + d0] = h;
}

extern "C" void kernel_launch(void* const* d_in, const int* in_sizes, int n_in,
                              void* d_out, int out_size, void* d_ws, size_t ws_size,
                              hipStream_t stream) {
  const float* x    = (const float*)d_in[0];
  const void*  rst  = d_in[1];
  const float* Wi   = (const float*)d_in[2];
  const float* bi   = (const float*)d_in[3];
  const float* Whr  = (const float*)d_in[4];
  const float* Whz  = (const float*)d_in[5];
  const float* Whn  = (const float*)d_in[6];
  const float* bhn  = (const float*)d_in[7];
  float* y = (float*)d_out;

  char* ws = (char*)d_ws;
  unsigned short* Wpk = (unsigned short*)(ws);              // 393216 B
  unsigned short* WiT = (unsigned short*)(ws + 393216);     // 393216 B
  float* hws          = (float*)(ws + 786432);              // 262144 B
  int* flags          = (int*)(ws + 1048576);               // 64 B
  int* rc             = (int*)(ws + 1048640);               // 64 B (16 rounds)
  unsigned char* rst8 = (unsigned char*)(ws + 1048832);     // 262144 B
  unsigned short* xpb = (unsigned short*)(ws + 1310976);

  const size_t fixed = 1310976;
  int Tc = T_DIM;
  while (Tc > 1 && fixed + (size_t)Tc * B_DIM * 768 * 2 > ws_size) Tc >>= 1;

  hipMemsetAsync(flags, 0, 8, stream);
  detect_resets<<<64, 256, 0, stream>>>((const int*)rst, T_DIM * B_DIM / 4, flags);
  convert_resets<<<256, 256, 0, stream>>>(rst, flags, rst8);
  pack_weights<<<1536, 256, 0, stream>>>(Wi, Whr, Whz, Whn, WiT, Wpk);
  for (int t0 = 0; t0 < T_DIM; t0 += Tc) {
    hipMemsetAsync(rc, 0, 64, stream);
    fused<<<256, 512, 0, stream>>>(x + (long)t0 * B_DIM * D_DIM, WiT, bi, xpb,
                                   rst8, bhn, Wpk, y, hws, rc, t0, Tc);
  }
}

// Round 12
// 1223.233 us; speedup vs baseline: 1.3985x; 1.3983x over previous
//
#include <hip/hip_runtime.h>

// GRU scan: T=1024, B=256, D=256.
// v11 = EXACT v7 restore (best measured: 1224us total). v8/v9/v10 each
// perturbed the scan loop's source schedule and regressed 100-450us:
//  - v8: pair-split DAG (2-acc ILP starved the MFMA pipe)
//  - v9: 3+3 half-split (extra LDS reads + fold-behind-MFMA dep stalls)
//  - v10: kk=0 peel + divergent paired stores (tail serialization)
// Lesson: the monolithic 6-acc interleave + scalar tail is the local optimum;
// the compiler pipelines it better than any hand-restructure. The 35.6M LDS
// "conflicts" are 2-way read aliasing = free (m136); HP=512 stays.

typedef __attribute__((ext_vector_type(8))) short short8;
typedef __attribute__((ext_vector_type(4))) float f32x4;

#define T_DIM 1024
#define B_DIM 256
#define D_DIM 256
#define SCL_RZ (-1.44269504f)   // -log2(e): sigm(x) = 1/(1+exp2(x*SCL_RZ))
#define SCL_N  (2.88539008f)    // 2*log2(e): tanh(v) = 1-2/(1+exp2(v*SCL_N))

__device__ __forceinline__ unsigned short f2bf(float f) {
  union { float f; unsigned u; } c; c.f = f;
  unsigned r = c.u + 0x7FFFu + ((c.u >> 16) & 1u);  // RNE
  return (unsigned short)(r >> 16);
}
__device__ __forceinline__ float u2f(unsigned u) {
  union { unsigned u; float f; } c; c.u = u;
  return c.f;
}
__device__ __forceinline__ float dpp_shr4(float own, float src) {
  union { float f; int i; } o, s, r;
  o.f = own; s.f = src;
  r.i = __builtin_amdgcn_update_dpp(o.i, s.i, 0x114, 0xF, 0xA, false);
  return r.f;
}
__device__ __forceinline__ float dpp_shr8(float own, float src) {
  union { float f; int i; } o, s, r;
  o.f = own; s.f = src;
  r.i = __builtin_amdgcn_update_dpp(o.i, s.i, 0x118, 0xF, 0xC, false);
  return r.f;
}
__device__ __forceinline__ float dpp_shr2(float x) {
  union { float f; int i; } s, r;
  s.f = x;
  r.i = __builtin_amdgcn_update_dpp(s.i, s.i, 0x112, 0xF, 0xF, false);
  return r.f;
}
// quad_perm [2,3,0,1]: lane q gets value from lane q^2 (pair partner)
__device__ __forceinline__ float dpp_swap2(float x) {
  union { float f; int i; } s, r;
  s.f = x;
  r.i = __builtin_amdgcn_update_dpp(s.i, s.i, 0x4E, 0xF, 0xF, false);
  return r.f;
}

// resets dtype ambiguous (reference dtype bool). flags[0]=float32, flags[1]=bytes.
__global__ void detect_resets(const int* __restrict__ r, int n, int* __restrict__ flags) {
  int isf = 0, oth = 0;
  for (int i = blockIdx.x * blockDim.x + threadIdx.x; i < n; i += gridDim.x * blockDim.x) {
    int v = r[i];
    if (v == 0x3F800000) isf = 1;
    else if (v != 0 && v != 1) oth = 1;
  }
  if (isf) atomicOr(&flags[0], 1);
  if (oth) atomicOr(&flags[1], 1);
}

__device__ __forceinline__ int read_reset(const void* r, int f0, int f1, int idx) {
  if (f0) return ((const float*)r)[idx] != 0.0f;
  if (f1) return ((const unsigned char*)r)[idx] != 0;
  return ((const int*)r)[idx] != 0;
}

__global__ void convert_resets(const void* __restrict__ rst, const int* __restrict__ flags,
                               unsigned char* __restrict__ rst8) {
  int f0 = flags[0], f1 = flags[1];
  for (int i = blockIdx.x * blockDim.x + threadIdx.x; i < T_DIM * B_DIM;
       i += gridDim.x * blockDim.x)
    rst8[i] = (unsigned char)read_reset(rst, f0, f1, i);
}

// Pack WiT (768x256 bf16, transposed Wi, PRE-SCALED per output col) and Wpk A-frags
// (PRE-SCALED): frag(dt,ks) elem (l,j) = scl(dt)*W[ks*32+(l>>4)*8+j][dt*16+(l&15)].
__global__ void pack_weights(const float* __restrict__ Wi,
                             const float* __restrict__ Whr,
                             const float* __restrict__ Whz,
                             const float* __restrict__ Whn,
                             unsigned short* __restrict__ WiT,
                             unsigned short* __restrict__ Wpk) {
  int gid = blockIdx.x * 256 + threadIdx.x;
  const int NE = 768 * 256;
  if (gid < NE) {
    int n = gid >> 8, k = gid & 255;
    float scl = (n < 512) ? SCL_RZ : SCL_N;
    WiT[gid] = f2bf(Wi[k * 768 + n] * scl);
  } else if (gid < 2 * NE) {
    int g = gid - NE;
    int j = g & 7, l = (g >> 3) & 63, ks = (g >> 9) & 7, nt = g >> 12;
    int k = ks * 32 + (l >> 4) * 8 + j;
    int col = nt * 16 + (l & 15);
    float w;
    if (col < 256)      w = Whr[k * 256 + col] * SCL_RZ;
    else if (col < 512) w = Whz[k * 256 + col - 256] * SCL_RZ;
    else                w = Whn[k * 256 + col - 512] * SCL_N;
    Wpk[g] = f2bf(w);
  }
}

// Fused kernel. even blockIdx -> scan WG (2 batch rows); odd -> producer WG.
// Producers compute xp in rounds of 128 m-blocks (64 t-steps), publish rc[r].
__global__ __launch_bounds__(512, 2) void fused(
    const float* __restrict__ x, const unsigned short* __restrict__ WiT,
    const float* __restrict__ bi, unsigned short* __restrict__ xp,
    const unsigned char* __restrict__ rst8, const float* __restrict__ bhn,
    const unsigned short* __restrict__ Wpk, float* __restrict__ y,
    float* __restrict__ hws, int* __restrict__ rc, int t0, int Tc) {
  __shared__ __align__(16) char smem[32768];
  const int tid = threadIdx.x;

  if (blockIdx.x & 1) {
    // ================= producer: xp = x@Wi_scaled + bi_scaled =================
    unsigned short* Al = (unsigned short*)smem;            // 128x64 bf16, swizzled
    unsigned short* Bl = (unsigned short*)(smem + 16384);  // 128x64 bf16, swizzled
    const int pw = blockIdx.x >> 1;
    const int l = tid & 63, wid = tid >> 6;
    const int wm = wid >> 2, wn = wid & 3;   // 2x4 wave grid over 128x128 tile
    const int Mc = Tc * 2;
    const int rounds = (Mc + 127) >> 7;
    for (int r = 0; r < rounds; ++r) {
      const int mb = r * 128 + pw;
      if (mb < Mc) {
        const long m0 = (long)mb * 128;
        for (int nb = 0; nb < 6; ++nb) {
          const int n0 = nb * 128;
          f32x4 acc[4][2] = {};
          for (int kb = 0; kb < 4; ++kb) {
            const int k0 = kb * 64;
            __syncthreads();
#pragma unroll
            for (int i = 0; i < 4; ++i) {  // stage A (x fp32 -> bf16)
              int fidx = i * 512 + tid;
              int row = fidx >> 4, kf = fidx & 15;
              float4 v = *(const float4*)&x[(m0 + row) * 256 + k0 + kf * 4];
              uint2 pk;
              pk.x = f2bf(v.x) | ((unsigned)f2bf(v.y) << 16);
              pk.y = f2bf(v.z) | ((unsigned)f2bf(v.w) << 16);
              int byte = (row * 128 + kf * 8) ^ ((row & 7) << 4);
              *(uint2*)((char*)Al + byte) = pk;
            }
#pragma unroll
            for (int i = 0; i < 2; ++i) {  // stage B (WiT bf16)
              int cidx = i * 512 + tid;
              int row = cidx >> 3, kc = cidx & 7;
              short8 v = *(const short8*)&WiT[(n0 + row) * 256 + k0 + kc * 8];
              int byte = (row * 128 + kc * 16) ^ ((row & 7) << 4);
              *(short8*)((char*)Bl + byte) = v;
            }
            __syncthreads();
#pragma unroll
            for (int kk = 0; kk < 2; ++kk) {
              short8 af[4], bfv[2];
#pragma unroll
              for (int t = 0; t < 4; ++t) {
                int m = wm * 64 + t * 16 + (l & 15);
                af[t] = *(const short8*)((char*)Al + ((m * 128 + kk * 64 + (l >> 4) * 16) ^ ((m & 7) << 4)));
              }
#pragma unroll
              for (int u = 0; u < 2; ++u) {
                int n = wn * 32 + u * 16 + (l & 15);
                bfv[u] = *(const short8*)((char*)Bl + ((n * 128 + kk * 64 + (l >> 4) * 16) ^ ((n & 7) << 4)));
              }
#pragma unroll
              for (int tm = 0; tm < 4; ++tm)
#pragma unroll
                for (int tn = 0; tn < 2; ++tn)
                  acc[tm][tn] = __builtin_amdgcn_mfma_f32_16x16x32_bf16(af[tm], bfv[tn], acc[tm][tn], 0, 0, 0);
            }
          }
#pragma unroll
          for (int tn = 0; tn < 2; ++tn) {
            int n = n0 + wn * 32 + tn * 16 + (l & 15);
            float bscl = bi[n] * ((n < 512) ? SCL_RZ : SCL_N);
#pragma unroll
            for (int tm = 0; tm < 4; ++tm) {
#pragma unroll
              for (int rr = 0; rr < 4; ++rr) {
                long m = m0 + wm * 64 + tm * 16 + (l >> 4) * 4 + rr;
                xp[m * 768 + n] = f2bf(acc[tm][tn][rr] + bscl);
              }
            }
          }
        }
      }
      __syncthreads();  // all waves' stores issued before the flag
      if (tid == 0)
        __hip_atomic_fetch_add(&rc[r], 1, __ATOMIC_RELEASE, __HIP_MEMORY_SCOPE_AGENT);
    }
    return;
  }

  // ================= consumer: recurrent scan (v6 body) =================
  unsigned short* hb16 = (unsigned short*)smem;  // [2][2*256] bf16, 2 KB
  const int l = tid & 63, w = tid >> 6;
  const int p = l & 15, grp = l >> 4;
  const int b = p & 1;
  const int B0 = (blockIdx.x >> 1) * 2;
  const bool odd1 = (p >> 1) & 1;
  const int d0 = w * 32 + ((p >> 2) & 1) * 16 + grp * 4 + ((p >> 3) & 1) * 2 + ((p >> 1) & 1);

  // all 48 weight frags into registers/AGPRs
  short8 wreg[48];
#pragma unroll
  for (int t = 0; t < 6; ++t) {
    int dt = (t >> 1) * 16 + w * 2 + (t & 1);
#pragma unroll
    for (int kk = 0; kk < 8; ++kk)
      wreg[t * 8 + kk] = *(const short8*)&Wpk[((dt * 8 + kk) * 64 + l) * 8];
  }
  const float bh = bhn[d0] * SCL_N;

  // init h (1 elem) + hb16[0]
  float h = 0.f;
  if (t0 > 0) {
    float hv = hws[(B0 + b) * 256 + d0];
    if (!rst8[t0 * 256 + B0 + b]) h = hv;
  }
  {
    unsigned hp;
    asm("v_cvt_pk_bf16_f32 %0, %1, %2" : "=v"(hp) : "v"(h), "v"(h));
    *(unsigned short*)((char*)hb16 + b * 512 + d0 * 2) = (unsigned short)hp;
  }
  __syncthreads();

  // wait for xp round 0, then prefetch step 0
  int done_rounds = 0;
#define WAIT_ROUNDS(rneed)                                                              \
  while (done_rounds <= (rneed)) {                                                     \
    int c_ = __hip_atomic_load(&rc[done_rounds], __ATOMIC_ACQUIRE,                     \
                               __HIP_MEMORY_SCOPE_AGENT);                              \
    if (c_ == 128) ++done_rounds;                                                      \
    else __builtin_amdgcn_s_sleep(8);                                                  \
  }
  WAIT_ROUNDS(0)

  const unsigned short* xpp = xp + ((long)(B0 + b)) * 768 + d0;
  float* yp = y + ((long)t0 * 256 + B0 + b) * 256 + d0;
  unsigned xr_ = *(const unsigned short*)(xpp);
  unsigned xz_ = *(const unsigned short*)(xpp + 256);
  unsigned xn_ = *(const unsigned short*)(xpp + 512);
  xpp += 256 * 768;
  int rstn = (t0 + 1 < T_DIM) ? (int)rst8[(t0 + 1) * 256 + B0 + b] : 0;
  const char* hrd = (const char*)hb16 + b * 512 + grp * 16;         // frag read base
  char* hwr = (char*)hb16 + b * 512 + d0 * 2;                       // merged write base (d0 even lanes)

  for (int ts = 0; ts < Tc; ++ts) {
    const int cur = ts & 1, nxt = cur ^ 1;
    const char* hb = hrd + cur * 1024;
    short8 hfr[3];
#define LD_H(k) (*(const short8*)(hb + (k) * 64))
    hfr[0] = LD_H(0);
    hfr[1] = LD_H(1);
    f32x4 acc[6] = {};
    __builtin_amdgcn_s_setprio(1);
#pragma unroll
    for (int kk = 0; kk < 8; ++kk) {
      if (kk + 2 < 8) hfr[(kk + 2) % 3] = LD_H(kk + 2);
      const int s = kk % 3;
      acc[0] = __builtin_amdgcn_mfma_f32_16x16x32_bf16(wreg[kk],      hfr[s], acc[0], 0, 0, 0);
      acc[1] = __builtin_amdgcn_mfma_f32_16x16x32_bf16(wreg[8 + kk],  hfr[s], acc[1], 0, 0, 0);
      acc[2] = __builtin_amdgcn_mfma_f32_16x16x32_bf16(wreg[16 + kk], hfr[s], acc[2], 0, 0, 0);
      acc[3] = __builtin_amdgcn_mfma_f32_16x16x32_bf16(wreg[24 + kk], hfr[s], acc[3], 0, 0, 0);
      acc[4] = __builtin_amdgcn_mfma_f32_16x16x32_bf16(wreg[32 + kk], hfr[s], acc[4], 0, 0, 0);
      acc[5] = __builtin_amdgcn_mfma_f32_16x16x32_bf16(wreg[40 + kk], hfr[s], acc[5], 0, 0, 0);
    }
    __builtin_amdgcn_s_setprio(0);
#undef LD_H
    // 3-stage fold: 6 tiles x 4 regs -> 1 elem/lane per gate
    float aR, aZ, aN;
    {
      float f0, f1, f2, f3, g0, g1;
      f0 = dpp_shr4(acc[0][0], acc[1][0]); f1 = dpp_shr4(acc[0][1], acc[1][1]);
      f2 = dpp_shr4(acc[0][2], acc[1][2]); f3 = dpp_shr4(acc[0][3], acc[1][3]);
      g0 = dpp_shr8(f0, f2); g1 = dpp_shr8(f1, f3);
      aR = odd1 ? dpp_shr2(g1) : g0;
      f0 = dpp_shr4(acc[2][0], acc[3][0]); f1 = dpp_shr4(acc[2][1], acc[3][1]);
      f2 = dpp_shr4(acc[2][2], acc[3][2]); f3 = dpp_shr4(acc[2][3], acc[3][3]);
      g0 = dpp_shr8(f0, f2); g1 = dpp_shr8(f1, f3);
      aZ = odd1 ? dpp_shr2(g1) : g0;
      f0 = dpp_shr4(acc[4][0], acc[5][0]); f1 = dpp_shr4(acc[4][1], acc[5][1]);
      f2 = dpp_shr4(acc[4][2], acc[5][2]); f3 = dpp_shr4(acc[4][3], acc[5][3]);
      g0 = dpp_shr8(f0, f2); g1 = dpp_shr8(f1, f3);
      aN = odd1 ? dpp_shr2(g1) : g0;
    }
    // gates: 1 elem, exp2-direct (3 exp2 + 2 rcp)
    float den_r = 1.0f + exp2f(fminf(u2f(xr_ << 16) + aR, 14.f));
    float den_z = 1.0f + exp2f(fminf(u2f(xz_ << 16) + aZ, 14.f));
    float s = __builtin_amdgcn_rcpf(den_r * den_z);
    float rg = den_z * s;   // 1/den_r
    float zg = den_r * s;   // 1/den_z
    float cden = 1.0f + exp2f(fminf(fmaf(rg, aN + bh, u2f(xn_ << 16)), 14.f));
    float ic = __builtin_amdgcn_rcpf(cden);
    float ng = fmaf(-2.0f, ic, 1.0f);            // tanh
    float o = fmaf(zg, h - ng, ng);              // o = n + z*(h-n)
    *yp = o;
    yp += 256 * 256;
    // carry (mask with next step's reset); pair-merged dword write to hb16[nxt]
    h = rstn ? 0.f : o;
    {
      float hq = dpp_swap2(h);   // partner lane (p^2) holds d0^1
      if ((p & 2) == 0) {        // even-d0 lanes write (h[d0], h[d0+1]) as one dword
        unsigned hp;
        asm("v_cvt_pk_bf16_f32 %0, %1, %2" : "=v"(hp) : "v"(h), "v"(hq));
        *(unsigned*)(hwr + nxt * 1024) = hp;
      }
    }
    // prefetch next step (vmcnt NOT drained at barrier)
    if (ts + 1 < Tc) {
      WAIT_ROUNDS((2 * ts + 3) >> 7)
      xr_ = *(const unsigned short*)(xpp);
      xz_ = *(const unsigned short*)(xpp + 256);
      xn_ = *(const unsigned short*)(xpp + 512);
      xpp += 256 * 768;
      int tg = t0 + ts;
      rstn = (tg + 2 < T_DIM) ? (int)rst8[(tg + 2) * 256 + B0 + b] : 0;
    }
    asm volatile("s_waitcnt lgkmcnt(0)" ::: "memory");
    __builtin_amdgcn_s_barrier();
  }
#undef WAIT_ROUNDS
  hws[(B0 + b) * 256 + d0] = h;
}

extern "C" void kernel_launch(void* const* d_in, const int* in_sizes, int n_in,
                              void* d_out, int out_size, void* d_ws, size_t ws_size,
                              hipStream_t stream) {
  const float* x    = (const float*)d_in[0];
  const void*  rst  = d_in[1];
  const float* Wi   = (const float*)d_in[2];
  const float* bi   = (const float*)d_in[3];
  const float* Whr  = (const float*)d_in[4];
  const float* Whz  = (const float*)d_in[5];
  const float* Whn  = (const float*)d_in[6];
  const float* bhn  = (const float*)d_in[7];
  float* y = (float*)d_out;

  char* ws = (char*)d_ws;
  unsigned short* Wpk = (unsigned short*)(ws);              // 393216 B
  unsigned short* WiT = (unsigned short*)(ws + 393216);     // 393216 B
  float* hws          = (float*)(ws + 786432);              // 262144 B
  int* flags          = (int*)(ws + 1048576);               // 64 B
  int* rc             = (int*)(ws + 1048640);               // 64 B (16 rounds)
  unsigned char* rst8 = (unsigned char*)(ws + 1048832);     // 262144 B
  unsigned short* xpb = (unsigned short*)(ws + 1310976);

  const size_t fixed = 1310976;
  int Tc = T_DIM;
  while (Tc > 1 && fixed + (size_t)Tc * B_DIM * 768 * 2 > ws_size) Tc >>= 1;

  hipMemsetAsync(flags, 0, 8, stream);
  detect_resets<<<64, 256, 0, stream>>>((const int*)rst, T_DIM * B_DIM / 4, flags);
  convert_resets<<<256, 256, 0, stream>>>(rst, flags, rst8);
  pack_weights<<<1536, 256, 0, stream>>>(Wi, Whr, Whz, Whn, WiT, Wpk);
  for (int t0 = 0; t0 < T_DIM; t0 += Tc) {
    hipMemsetAsync(rc, 0, 64, stream);
    fused<<<256, 512, 0, stream>>>(x + (long)t0 * B_DIM * D_DIM, WiT, bi, xpb,
                                   rst8, bhn, Wpk, y, hws, rc, t0, Tc);
  }
}